// Round 1
// baseline (1067.648 us; speedup 1.0000x reference)
//
#include <hip/hip_runtime.h>

#define B_ 16
#define C_ 256
#define N_ 2304
#define QD_ 64
#define VD_ 256

typedef unsigned short u16;
typedef __attribute__((ext_vector_type(8))) short bf16x8;
typedef __attribute__((ext_vector_type(4))) float f32x4;
typedef __attribute__((ext_vector_type(4))) u16 u16x4;

__device__ inline u16 f2b(float f){
  unsigned u = __builtin_bit_cast(unsigned, f);
  return (u16)((u + 0x7FFFu + ((u >> 16) & 1u)) >> 16);
}

// ---------------- K1a: weights -> bf16 ----------------
__global__ void prep_weights(const float* __restrict__ Wq, const float* __restrict__ Wk,
                             const float* __restrict__ Wv, const float* __restrict__ Wo,
                             u16* __restrict__ W_all, u16* __restrict__ Wo_bf){
  int i = blockIdx.x * 256 + threadIdx.x;   // 0 .. 98303
  int row = i >> 8;
  float val;
  if (row < 64) val = Wq[i];
  else if (row < 128) val = Wk[i - 64*C_];
  else val = Wv[i - 128*C_];
  W_all[i] = f2b(val);
  if (i < C_*VD_) Wo_bf[i] = f2b(Wo[i]);
}

// ---------------- K1b: x [b][c][n] f32 -> x_t [b][n][c] bf16 ----------------
__global__ void transpose_x(const float* __restrict__ x, u16* __restrict__ x_t){
  __shared__ float tile[64][65];
  int b = blockIdx.z;
  int c0 = blockIdx.y * 64, n0 = blockIdx.x * 64;
  int tx = threadIdx.x & 63, ty = threadIdx.x >> 6;
  const float* xb = x + (size_t)b * C_ * N_;
  #pragma unroll
  for (int rr = 0; rr < 16; ++rr){
    int c = ty*16 + rr;
    tile[c][tx] = xb[(size_t)(c0 + c) * N_ + n0 + tx];
  }
  __syncthreads();
  u16* xtb = x_t + (size_t)b * N_ * C_;
  #pragma unroll
  for (int rr = 0; rr < 16; ++rr){
    int n = ty*16 + rr;
    xtb[(size_t)(n0 + n) * C_ + c0 + tx] = f2b(tile[tx][n]);
  }
}

// ---------------- shared 64x64-per-wave MFMA core ----------------
// D[m][n] = sum_k A[m][k] * Bt[n][k];  A: [.. ][KD] bf16 row-major (pre-offset to m0),
// Bt: [..][KD] bf16 row-major (pre-offset to n0). Wave computes 64x64 (4x4 tiles).
template<int KD>
__device__ inline void mfma_tile64(const u16* __restrict__ A, const u16* __restrict__ Bt,
                                   f32x4 acc[4][4], int lane){
  int cl = lane & 15, q = lane >> 4;
  const u16* ab = A + cl*KD + q*8;
  const u16* bb = Bt + cl*KD + q*8;
  for (int kk = 0; kk < KD/32; ++kk){
    bf16x8 a[4], bfr[4];
    #pragma unroll
    for (int t = 0; t < 4; ++t) a[t] = *(const bf16x8*)(ab + t*16*KD + kk*32);
    #pragma unroll
    for (int t = 0; t < 4; ++t) bfr[t] = *(const bf16x8*)(bb + t*16*KD + kk*32);
    #pragma unroll
    for (int tm = 0; tm < 4; ++tm)
      #pragma unroll
      for (int tn = 0; tn < 4; ++tn)
        acc[tm][tn] = __builtin_amdgcn_mfma_f32_16x16x32_bf16(a[tm], bfr[tn], acc[tm][tn], 0, 0, 0);
  }
}

// ---------------- K2: qkv = W_all @ x  (per batch) ----------------
// q_t[b][n][64], k_t[b][n][64] (transposed), v[b][vd][n] (normal), all bf16 + bias
__global__ __launch_bounds__(512) void qkv_gemm(const u16* __restrict__ W_all, const u16* __restrict__ x_t,
    const float* __restrict__ bq, const float* __restrict__ bk, const float* __restrict__ bv,
    u16* __restrict__ q_t, u16* __restrict__ k_t, u16* __restrict__ v){
  int b = blockIdx.z;
  int lane = threadIdx.x & 63, wid = threadIdx.x >> 6;
  int m0 = blockIdx.x*128 + (wid >> 2)*64;
  int n0 = blockIdx.y*256 + (wid & 3)*64;
  const u16* xtb = x_t + (size_t)b*N_*C_;
  f32x4 acc[4][4] = {};
  mfma_tile64<C_>(W_all + (size_t)m0*C_, xtb + (size_t)n0*C_, acc, lane);
  int cl = lane & 15, q = lane >> 4;
  size_t qb = (size_t)b*N_*QD_;
  u16* vb = v + (size_t)b*VD_*N_;
  #pragma unroll
  for (int tm = 0; tm < 4; ++tm){
    int m = m0 + tm*16 + q*4;
    #pragma unroll
    for (int tn = 0; tn < 4; ++tn){
      int n = n0 + tn*16 + cl;
      f32x4 d = acc[tm][tn];
      if (m0 < 64){
        u16x4 pk;
        #pragma unroll
        for (int r = 0; r < 4; ++r) pk[r] = f2b(d[r] + bq[m + r]);
        *(u16x4*)(q_t + qb + (size_t)n*QD_ + m) = pk;
      } else if (m0 < 128){
        u16x4 pk;
        #pragma unroll
        for (int r = 0; r < 4; ++r) pk[r] = f2b(d[r] + bk[m - 64 + r]);
        *(u16x4*)(k_t + qb + (size_t)n*QD_ + (m - 64)) = pk;
      } else {
        #pragma unroll
        for (int r = 0; r < 4; ++r) vb[(size_t)(m - 128 + r)*N_ + n] = f2b(d[r] + bv[m - 128 + r]);
      }
    }
  }
}

// ---------------- K3a: energy[b][i][j] = q_t[i][:] . k_t[j][:] (f32 out) ----------------
__global__ __launch_bounds__(512) void energy_gemm(const u16* __restrict__ q_t, const u16* __restrict__ k_t,
                                                   float* __restrict__ attn){
  int b = blockIdx.z;
  int lane = threadIdx.x & 63, wid = threadIdx.x >> 6;
  int i0 = blockIdx.x*128 + (wid >> 2)*64;
  int j0 = blockIdx.y*256 + (wid & 3)*64;
  size_t qb = (size_t)b*N_*QD_;
  f32x4 acc[4][4] = {};
  mfma_tile64<QD_>(q_t + qb + (size_t)i0*QD_, k_t + qb + (size_t)j0*QD_, acc, lane);
  float* ab = attn + (size_t)b*N_*N_;
  int cl = lane & 15, q = lane >> 4;
  #pragma unroll
  for (int tm = 0; tm < 4; ++tm){
    int i = i0 + tm*16 + q*4;
    #pragma unroll
    for (int tn = 0; tn < 4; ++tn){
      int j = j0 + tn*16 + cl;
      #pragma unroll
      for (int r = 0; r < 4; ++r) ab[(size_t)(i + r)*N_ + j] = acc[tm][tn][r];
    }
  }
}

// ---------------- K3b: in-place row softmax over j ----------------
__global__ __launch_bounds__(256) void softmax_rows(float* __restrict__ attn){
  int i = blockIdx.x, b = blockIdx.y;
  float* row = attn + ((size_t)b*N_ + i)*N_;
  int t = threadIdx.x;
  int lane = t & 63, wid = t >> 6;
  float v[9];
  float mx = -3.0e38f;
  #pragma unroll
  for (int k = 0; k < 9; ++k){ v[k] = row[t + k*256]; mx = fmaxf(mx, v[k]); }
  #pragma unroll
  for (int off = 1; off < 64; off <<= 1) mx = fmaxf(mx, __shfl_xor(mx, off));
  __shared__ float redm[4], reds[4];
  if (lane == 0) redm[wid] = mx;
  __syncthreads();
  mx = fmaxf(fmaxf(redm[0], redm[1]), fmaxf(redm[2], redm[3]));
  float s = 0.f;
  #pragma unroll
  for (int k = 0; k < 9; ++k){ v[k] = __expf(v[k] - mx); s += v[k]; }
  #pragma unroll
  for (int off = 1; off < 64; off <<= 1) s += __shfl_xor(s, off);
  if (lane == 0) reds[wid] = s;
  __syncthreads();
  s = reds[0] + reds[1] + reds[2] + reds[3];
  float inv = 1.0f / s;
  #pragma unroll
  for (int k = 0; k < 9; ++k) row[t + k*256] = v[k] * inv;
}

// ---------------- K4: o_t[b][i][vd] = sum_j attn[i][j] * v[vd][j] ----------------
__device__ inline bf16x8 pack8(f32x4 lo, f32x4 hi){
  bf16x8 r;
  #pragma unroll
  for (int i = 0; i < 4; ++i){ r[i] = (short)f2b(lo[i]); r[i+4] = (short)f2b(hi[i]); }
  return r;
}

__global__ __launch_bounds__(512) void pv_gemm(const float* __restrict__ attn, const u16* __restrict__ v,
                                               u16* __restrict__ o_t){
  int b = blockIdx.z;
  int lane = threadIdx.x & 63, wid = threadIdx.x >> 6;
  int i0 = blockIdx.x*128 + (wid >> 2)*64;
  int vd0 = (wid & 3)*64;
  const float* ab = attn + (size_t)b*N_*N_;
  const u16* vb = v + (size_t)b*VD_*N_;
  int cl = lane & 15, q = lane >> 4;
  const float* arow = ab + (size_t)(i0 + cl)*N_ + q*8;
  const u16* bb = vb + (size_t)(vd0 + cl)*N_ + q*8;
  f32x4 acc[4][4] = {};
  for (int kk = 0; kk < N_/32; ++kk){
    bf16x8 a[4], bfr[4];
    #pragma unroll
    for (int t = 0; t < 4; ++t){
      const float* p = arow + (size_t)t*16*N_ + kk*32;
      a[t] = pack8(*(const f32x4*)p, *(const f32x4*)(p + 4));
    }
    #pragma unroll
    for (int t = 0; t < 4; ++t) bfr[t] = *(const bf16x8*)(bb + (size_t)t*16*N_ + kk*32);
    #pragma unroll
    for (int tm = 0; tm < 4; ++tm)
      #pragma unroll
      for (int tn = 0; tn < 4; ++tn)
        acc[tm][tn] = __builtin_amdgcn_mfma_f32_16x16x32_bf16(a[tm], bfr[tn], acc[tm][tn], 0, 0, 0);
  }
  u16* ob = o_t + (size_t)b*N_*VD_;
  #pragma unroll
  for (int tm = 0; tm < 4; ++tm){
    int i = i0 + tm*16 + q*4;
    #pragma unroll
    for (int tn = 0; tn < 4; ++tn){
      int vd = vd0 + tn*16 + cl;
      #pragma unroll
      for (int r = 0; r < 4; ++r) ob[(size_t)(i + r)*VD_ + vd] = f2b(acc[tm][tn][r]);
    }
  }
}

// ---------------- K5: out = gamma*(Wo @ o + bo) + x ----------------
__global__ __launch_bounds__(512) void out_gemm(const u16* __restrict__ Wo_bf, const u16* __restrict__ o_t,
    const float* __restrict__ bo, const float* __restrict__ gamma,
    const float* __restrict__ x, float* __restrict__ out){
  int b = blockIdx.z;
  int lane = threadIdx.x & 63, wid = threadIdx.x >> 6;
  int c0 = blockIdx.x*128 + (wid >> 2)*64;
  int n0 = blockIdx.y*256 + (wid & 3)*64;
  f32x4 acc[4][4] = {};
  mfma_tile64<VD_>(Wo_bf + (size_t)c0*VD_, o_t + (size_t)b*N_*VD_ + (size_t)n0*VD_, acc, lane);
  float g = gamma[0];
  const float* xb = x + (size_t)b*C_*N_;
  float* ob = out + (size_t)b*C_*N_;
  int cl = lane & 15, q = lane >> 4;
  #pragma unroll
  for (int tm = 0; tm < 4; ++tm){
    int c = c0 + tm*16 + q*4;
    #pragma unroll
    for (int tn = 0; tn < 4; ++tn){
      int n = n0 + tn*16 + cl;
      #pragma unroll
      for (int r = 0; r < 4; ++r){
        size_t idx = (size_t)(c + r)*N_ + n;
        ob[idx] = g*(acc[tm][tn][r] + bo[c + r]) + xb[idx];
      }
    }
  }
}

extern "C" void kernel_launch(void* const* d_in, const int* in_sizes, int n_in,
                              void* d_out, int out_size, void* d_ws, size_t ws_size,
                              hipStream_t stream){
  const float* x     = (const float*)d_in[0];
  const float* Wq    = (const float*)d_in[1];
  const float* bq    = (const float*)d_in[2];
  const float* Wk    = (const float*)d_in[3];
  const float* bk    = (const float*)d_in[4];
  const float* Wv    = (const float*)d_in[5];
  const float* bv    = (const float*)d_in[6];
  const float* Wo    = (const float*)d_in[7];
  const float* bo    = (const float*)d_in[8];
  const float* gamma = (const float*)d_in[9];

  float* out  = (float*)d_out;
  float* attn = out + (size_t)B_*C_*N_;   // 9,437,184 floats in

  char* ws = (char*)d_ws;
  u16* W_all = (u16*)(ws + 0);             // 384*256          = 196,608 B
  u16* Wo_bf = (u16*)(ws + 196608);        // 256*256          = 131,072 B
  u16* x_t   = (u16*)(ws + 327680);        // B*N*C bf16       = 18,874,368 B
  u16* q_t   = (u16*)(ws + 19202048);      // B*N*64           = 4,718,592 B
  u16* k_t   = (u16*)(ws + 23920640);      // B*N*64           = 4,718,592 B
  u16* v     = (u16*)(ws + 28639232);      // B*256*N          = 18,874,368 B
  u16* o_t   = (u16*)(ws + 47513600);      // B*N*256          = 18,874,368 B  (end 66,387,968)

  prep_weights<<<dim3(384), 256, 0, stream>>>(Wq, Wk, Wv, Wo, W_all, Wo_bf);
  transpose_x<<<dim3(36, 4, 16), 256, 0, stream>>>(x, x_t);
  qkv_gemm<<<dim3(3, 9, 16), 512, 0, stream>>>(W_all, x_t, bq, bk, bv, q_t, k_t, v);
  energy_gemm<<<dim3(18, 9, 16), 512, 0, stream>>>(q_t, k_t, attn);
  softmax_rows<<<dim3(2304, 16), 256, 0, stream>>>(attn);
  pv_gemm<<<dim3(18, 1, 16), 512, 0, stream>>>(attn, v, o_t);
  out_gemm<<<dim3(2, 9, 16), 512, 0, stream>>>(Wo_bf, o_t, bo, gamma, x, out);
}

// Round 5
// 878.246 us; speedup vs baseline: 1.2157x; 1.2157x over previous
//
#include <hip/hip_runtime.h>

#define B_ 16
#define C_ 256
#define N_ 2304
#define QD_ 64
#define VD_ 256

typedef unsigned short u16;
typedef __attribute__((ext_vector_type(8))) short bf16x8;
typedef __attribute__((ext_vector_type(4))) float f32x4;
typedef __attribute__((ext_vector_type(4))) u16 u16x4;

__device__ inline u16 f2b(float f){
  unsigned u = __builtin_bit_cast(unsigned, f);
  return (u16)((u + 0x7FFFu + ((u >> 16) & 1u)) >> 16);
}

// ---------------- K1a: weights -> bf16 ----------------
__global__ void prep_weights(const float* __restrict__ Wq, const float* __restrict__ Wk,
                             const float* __restrict__ Wv, const float* __restrict__ Wo,
                             u16* __restrict__ W_all, u16* __restrict__ Wo_bf){
  int i = blockIdx.x * 256 + threadIdx.x;   // 0 .. 98303
  int row = i >> 8;
  float val;
  if (row < 64) val = Wq[i];
  else if (row < 128) val = Wk[i - 64*C_];
  else val = Wv[i - 128*C_];
  W_all[i] = f2b(val);
  if (i < C_*VD_) Wo_bf[i] = f2b(Wo[i]);
}

// ---------------- K1b: x [b][c][n] f32 -> x_t [b][n][c] bf16 ----------------
__global__ void transpose_x(const float* __restrict__ x, u16* __restrict__ x_t){
  __shared__ float tile[64][65];
  int b = blockIdx.z;
  int c0 = blockIdx.y * 64, n0 = blockIdx.x * 64;
  int tx = threadIdx.x & 63, ty = threadIdx.x >> 6;
  const float* xb = x + (size_t)b * C_ * N_;
  #pragma unroll
  for (int rr = 0; rr < 16; ++rr){
    int c = ty*16 + rr;
    tile[c][tx] = xb[(size_t)(c0 + c) * N_ + n0 + tx];
  }
  __syncthreads();
  u16* xtb = x_t + (size_t)b * N_ * C_;
  #pragma unroll
  for (int rr = 0; rr < 16; ++rr){
    int n = ty*16 + rr;
    xtb[(size_t)(n0 + n) * C_ + c0 + tx] = f2b(tile[tx][n]);
  }
}

// ---------------- shared 64x64-per-wave MFMA core ----------------
// D[m][n] = sum_k A[m][k] * Bt[n][k];  A, Bt row-major with row stride KD,
// K extent KD. Wave computes 64x64 (4x4 tiles of 16x16x32 MFMA).
template<int KD>
__device__ inline void mfma_tile64(const u16* __restrict__ A, const u16* __restrict__ Bt,
                                   f32x4 acc[4][4], int lane){
  int cl = lane & 15, q = lane >> 4;
  const u16* ab = A + cl*KD + q*8;
  const u16* bb = Bt + cl*KD + q*8;
  for (int kk = 0; kk < KD/32; ++kk){
    bf16x8 a[4], bfr[4];
    #pragma unroll
    for (int t = 0; t < 4; ++t) a[t] = *(const bf16x8*)(ab + t*16*KD + kk*32);
    #pragma unroll
    for (int t = 0; t < 4; ++t) bfr[t] = *(const bf16x8*)(bb + t*16*KD + kk*32);
    #pragma unroll
    for (int tm = 0; tm < 4; ++tm)
      #pragma unroll
      for (int tn = 0; tn < 4; ++tn)
        acc[tm][tn] = __builtin_amdgcn_mfma_f32_16x16x32_bf16(a[tm], bfr[tn], acc[tm][tn], 0, 0, 0);
  }
}

// ---------------- K2: qkv = W_all @ x  (per batch) ----------------
__global__ __launch_bounds__(512) void qkv_gemm(const u16* __restrict__ W_all, const u16* __restrict__ x_t,
    const float* __restrict__ bq, const float* __restrict__ bk, const float* __restrict__ bv,
    u16* __restrict__ q_t, u16* __restrict__ k_t, u16* __restrict__ v){
  int b = blockIdx.z;
  int lane = threadIdx.x & 63, wid = threadIdx.x >> 6;
  int m0 = blockIdx.x*128 + (wid >> 2)*64;
  int n0 = blockIdx.y*256 + (wid & 3)*64;
  const u16* xtb = x_t + (size_t)b*N_*C_;
  f32x4 acc[4][4] = {};
  mfma_tile64<C_>(W_all + (size_t)m0*C_, xtb + (size_t)n0*C_, acc, lane);
  int cl = lane & 15, q = lane >> 4;
  size_t qb = (size_t)b*N_*QD_;
  u16* vb = v + (size_t)b*VD_*N_;
  #pragma unroll
  for (int tm = 0; tm < 4; ++tm){
    int m = m0 + tm*16 + q*4;
    #pragma unroll
    for (int tn = 0; tn < 4; ++tn){
      int n = n0 + tn*16 + cl;
      f32x4 d = acc[tm][tn];
      if (m0 < 64){
        u16x4 pk;
        #pragma unroll
        for (int r = 0; r < 4; ++r) pk[r] = f2b(d[r] + bq[m + r]);
        *(u16x4*)(q_t + qb + (size_t)n*QD_ + m) = pk;
      } else if (m0 < 128){
        u16x4 pk;
        #pragma unroll
        for (int r = 0; r < 4; ++r) pk[r] = f2b(d[r] + bk[m - 64 + r]);
        *(u16x4*)(k_t + qb + (size_t)n*QD_ + (m - 64)) = pk;
      } else {
        #pragma unroll
        for (int r = 0; r < 4; ++r) vb[(size_t)(m - 128 + r)*N_ + n] = f2b(d[r] + bv[m - 128 + r]);
      }
    }
  }
}

// ---------------- K3a: energy[b][i][j] = q_t[i][:] . k_t[j][:] (f32 out) ----------------
__global__ __launch_bounds__(512) void energy_gemm(const u16* __restrict__ q_t, const u16* __restrict__ k_t,
                                                   float* __restrict__ attn){
  int b = blockIdx.z;
  int lane = threadIdx.x & 63, wid = threadIdx.x >> 6;
  int i0 = blockIdx.x*128 + (wid >> 2)*64;
  int j0 = blockIdx.y*256 + (wid & 3)*64;
  size_t qb = (size_t)b*N_*QD_;
  f32x4 acc[4][4] = {};
  mfma_tile64<QD_>(q_t + qb + (size_t)i0*QD_, k_t + qb + (size_t)j0*QD_, acc, lane);
  float* ab = attn + (size_t)b*N_*N_;
  int cl = lane & 15, q = lane >> 4;
  #pragma unroll
  for (int tm = 0; tm < 4; ++tm){
    int i = i0 + tm*16 + q*4;
    #pragma unroll
    for (int tn = 0; tn < 4; ++tn){
      int j = j0 + tn*16 + cl;
      #pragma unroll
      for (int r = 0; r < 4; ++r) ab[(size_t)(i + r)*N_ + j] = acc[tm][tn][r];
    }
  }
}

// ---------------- K3b: row softmax; writes final f32 attn + bf16 copy ----------------
// one row per block: 576 threads, each owns one f32x4 (2304 = 576*4)
__global__ __launch_bounds__(576) void softmax_rows(float* __restrict__ attn, u16* __restrict__ attn_bf){
  int i = blockIdx.x, b = blockIdx.y;
  size_t base = ((size_t)b*N_ + i)*N_;
  float* row = attn + base;
  u16* brow = attn_bf + base;
  int t = threadIdx.x;
  int lane = t & 63, wid = t >> 6;
  f32x4 v = *(const f32x4*)(row + t*4);
  float mx = fmaxf(fmaxf(v[0], v[1]), fmaxf(v[2], v[3]));
  #pragma unroll
  for (int off = 1; off < 64; off <<= 1) mx = fmaxf(mx, __shfl_xor(mx, off));
  __shared__ float redm[9], reds[9];
  if (lane == 0) redm[wid] = mx;
  __syncthreads();
  mx = redm[0];
  #pragma unroll
  for (int k = 1; k < 9; ++k) mx = fmaxf(mx, redm[k]);
  float s = 0.f;
  #pragma unroll
  for (int k = 0; k < 4; ++k){ v[k] = __expf(v[k] - mx); s += v[k]; }
  #pragma unroll
  for (int off = 1; off < 64; off <<= 1) s += __shfl_xor(s, off);
  if (lane == 0) reds[wid] = s;
  __syncthreads();
  s = reds[0];
  #pragma unroll
  for (int k = 1; k < 9; ++k) s += reds[k];
  float inv = 1.0f / s;
  u16x4 pk;
  #pragma unroll
  for (int k = 0; k < 4; ++k){ v[k] *= inv; pk[k] = f2b(v[k]); }
  *(f32x4*)(row + t*4) = v;
  *(u16x4*)(brow + t*4) = pk;
}

// ---------------- K4: o_t[b][i][vd] = sum_j attn_bf[i][j] * v[vd][j] ----------------
__global__ __launch_bounds__(256) void pv_gemm(const u16* __restrict__ attn_bf, const u16* __restrict__ v,
                                               u16* __restrict__ o_t){
  int b = blockIdx.z;
  int lane = threadIdx.x & 63, wid = threadIdx.x >> 6;
  int i0 = blockIdx.x*128 + (wid >> 1)*64;
  int vd0 = blockIdx.y*128 + (wid & 1)*64;
  const u16* ab = attn_bf + (size_t)b*N_*N_;
  const u16* vb = v + (size_t)b*VD_*N_;
  f32x4 acc[4][4] = {};
  mfma_tile64<N_>(ab + (size_t)i0*N_, vb + (size_t)vd0*N_, acc, lane);
  u16* ob = o_t + (size_t)b*N_*VD_;
  int cl = lane & 15, q = lane >> 4;
  #pragma unroll
  for (int tm = 0; tm < 4; ++tm){
    int i = i0 + tm*16 + q*4;
    #pragma unroll
    for (int tn = 0; tn < 4; ++tn){
      int vd = vd0 + tn*16 + cl;
      #pragma unroll
      for (int r = 0; r < 4; ++r) ob[(size_t)(i + r)*VD_ + vd] = f2b(acc[tm][tn][r]);
    }
  }
}

// ---------------- K5: out = gamma*(Wo @ o + bo) + x ----------------
__global__ __launch_bounds__(512) void out_gemm(const u16* __restrict__ Wo_bf, const u16* __restrict__ o_t,
    const float* __restrict__ bo, const float* __restrict__ gamma,
    const float* __restrict__ x, float* __restrict__ out){
  int b = blockIdx.z;
  int lane = threadIdx.x & 63, wid = threadIdx.x >> 6;
  int c0 = blockIdx.x*128 + (wid >> 2)*64;
  int n0 = blockIdx.y*256 + (wid & 3)*64;
  f32x4 acc[4][4] = {};
  mfma_tile64<VD_>(Wo_bf + (size_t)c0*VD_, o_t + (size_t)b*N_*VD_ + (size_t)n0*VD_, acc, lane);
  float g = gamma[0];
  const float* xb = x + (size_t)b*C_*N_;
  float* ob = out + (size_t)b*C_*N_;
  int cl = lane & 15, q = lane >> 4;
  #pragma unroll
  for (int tm = 0; tm < 4; ++tm){
    int c = c0 + tm*16 + q*4;
    #pragma unroll
    for (int tn = 0; tn < 4; ++tn){
      int n = n0 + tn*16 + cl;
      #pragma unroll
      for (int r = 0; r < 4; ++r){
        size_t idx = (size_t)(c + r)*N_ + n;
        ob[idx] = g*(acc[tm][tn][r] + bo[c + r]) + xb[idx];
      }
    }
  }
}

extern "C" void kernel_launch(void* const* d_in, const int* in_sizes, int n_in,
                              void* d_out, int out_size, void* d_ws, size_t ws_size,
                              hipStream_t stream){
  const float* x     = (const float*)d_in[0];
  const float* Wq    = (const float*)d_in[1];
  const float* bq    = (const float*)d_in[2];
  const float* Wk    = (const float*)d_in[3];
  const float* bk    = (const float*)d_in[4];
  const float* Wv    = (const float*)d_in[5];
  const float* bv    = (const float*)d_in[6];
  const float* Wo    = (const float*)d_in[7];
  const float* bo    = (const float*)d_in[8];
  const float* gamma = (const float*)d_in[9];

  float* out  = (float*)d_out;
  float* attn = out + (size_t)B_*C_*N_;

  char* ws = (char*)d_ws;
  u16* W_all   = (u16*)(ws + 0);             // 196,608 B
  u16* Wo_bf   = (u16*)(ws + 196608);        // 131,072 B -> 327,680
  u16* x_t     = (u16*)(ws + 327680);        // 18,874,368 -> 19,202,048
  u16* q_t     = (u16*)(ws + 19202048);      // 4,718,592  -> 23,920,640
  u16* k_t     = (u16*)(ws + 23920640);      // 4,718,592  -> 28,639,232
  u16* v       = (u16*)(ws + 28639232);      // 18,874,368 -> 47,513,600
  u16* o_t     = (u16*)(ws + 47513600);      // 18,874,368 -> 66,387,968
  u16* attn_bf = (u16*)(ws + 66387968);      // B*N*N*2 = 169,869,312 -> 236,257,280

  prep_weights<<<dim3(384), 256, 0, stream>>>(Wq, Wk, Wv, Wo, W_all, Wo_bf);
  transpose_x<<<dim3(36, 4, 16), 256, 0, stream>>>(x, x_t);
  qkv_gemm<<<dim3(3, 9, 16), 512, 0, stream>>>(W_all, x_t, bq, bk, bv, q_t, k_t, v);
  energy_gemm<<<dim3(18, 9, 16), 512, 0, stream>>>(q_t, k_t, attn);
  softmax_rows<<<dim3(2304, 16), 576, 0, stream>>>(attn, attn_bf);
  pv_gemm<<<dim3(18, 2, 16), 256, 0, stream>>>(attn_bf, v, o_t);
  out_gemm<<<dim3(2, 9, 16), 512, 0, stream>>>(Wo_bf, o_t, bo, gamma, x, out);
}

// Round 7
// 872.392 us; speedup vs baseline: 1.2238x; 1.0067x over previous
//
#include <hip/hip_runtime.h>

#define B_ 16
#define C_ 256
#define N_ 2304
#define QD_ 64
#define VD_ 256

typedef unsigned short u16;
typedef __attribute__((ext_vector_type(8))) short bf16x8;
typedef __attribute__((ext_vector_type(4))) float f32x4;
typedef __attribute__((ext_vector_type(4))) u16 u16x4;

__device__ inline u16 f2b(float f){
  unsigned u = __builtin_bit_cast(unsigned, f);
  return (u16)((u + 0x7FFFu + ((u >> 16) & 1u)) >> 16);
}

// ---------------- K1a: weights -> bf16 ----------------
__global__ void prep_weights(const float* __restrict__ Wq, const float* __restrict__ Wk,
                             const float* __restrict__ Wv, const float* __restrict__ Wo,
                             u16* __restrict__ W_all, u16* __restrict__ Wo_bf){
  int i = blockIdx.x * 256 + threadIdx.x;   // 0 .. 98303
  int row = i >> 8;
  float val;
  if (row < 64) val = Wq[i];
  else if (row < 128) val = Wk[i - 64*C_];
  else val = Wv[i - 128*C_];
  W_all[i] = f2b(val);
  if (i < C_*VD_) Wo_bf[i] = f2b(Wo[i]);
}

// ---------------- K1b: x [b][c][n] f32 -> x_t [b][n][c] bf16 ----------------
__global__ void transpose_x(const float* __restrict__ x, u16* __restrict__ x_t){
  __shared__ float tile[64][65];
  int b = blockIdx.z;
  int c0 = blockIdx.y * 64, n0 = blockIdx.x * 64;
  int tx = threadIdx.x & 63, ty = threadIdx.x >> 6;
  const float* xb = x + (size_t)b * C_ * N_;
  #pragma unroll
  for (int rr = 0; rr < 16; ++rr){
    int c = ty*16 + rr;
    tile[c][tx] = xb[(size_t)(c0 + c) * N_ + n0 + tx];
  }
  __syncthreads();
  u16* xtb = x_t + (size_t)b * N_ * C_;
  #pragma unroll
  for (int rr = 0; rr < 16; ++rr){
    int n = ty*16 + rr;
    xtb[(size_t)(n0 + n) * C_ + c0 + tx] = f2b(tile[tx][n]);
  }
}

// ---------------- shared 64x64-per-wave MFMA core ----------------
template<int KD>
__device__ inline void mfma_tile64(const u16* __restrict__ A, const u16* __restrict__ Bt,
                                   f32x4 acc[4][4], int lane){
  int cl = lane & 15, q = lane >> 4;
  const u16* ab = A + cl*KD + q*8;
  const u16* bb = Bt + cl*KD + q*8;
  for (int kk = 0; kk < KD/32; ++kk){
    bf16x8 a[4], bfr[4];
    #pragma unroll
    for (int t = 0; t < 4; ++t) a[t] = *(const bf16x8*)(ab + t*16*KD + kk*32);
    #pragma unroll
    for (int t = 0; t < 4; ++t) bfr[t] = *(const bf16x8*)(bb + t*16*KD + kk*32);
    #pragma unroll
    for (int tm = 0; tm < 4; ++tm)
      #pragma unroll
      for (int tn = 0; tn < 4; ++tn)
        acc[tm][tn] = __builtin_amdgcn_mfma_f32_16x16x32_bf16(a[tm], bfr[tn], acc[tm][tn], 0, 0, 0);
  }
}

// ---------------- K2: qkv = W_all @ x  (per batch) ----------------
__global__ __launch_bounds__(512) void qkv_gemm(const u16* __restrict__ W_all, const u16* __restrict__ x_t,
    const float* __restrict__ bq, const float* __restrict__ bk, const float* __restrict__ bv,
    u16* __restrict__ q_t, u16* __restrict__ k_t, u16* __restrict__ v){
  int b = blockIdx.z;
  int lane = threadIdx.x & 63, wid = threadIdx.x >> 6;
  int m0 = blockIdx.x*128 + (wid >> 2)*64;
  int n0 = blockIdx.y*256 + (wid & 3)*64;
  const u16* xtb = x_t + (size_t)b*N_*C_;
  f32x4 acc[4][4] = {};
  mfma_tile64<C_>(W_all + (size_t)m0*C_, xtb + (size_t)n0*C_, acc, lane);
  int cl = lane & 15, q = lane >> 4;
  size_t qb = (size_t)b*N_*QD_;
  u16* vb = v + (size_t)b*VD_*N_;
  #pragma unroll
  for (int tm = 0; tm < 4; ++tm){
    int m = m0 + tm*16 + q*4;
    #pragma unroll
    for (int tn = 0; tn < 4; ++tn){
      int n = n0 + tn*16 + cl;
      f32x4 d = acc[tm][tn];
      if (m0 < 64){
        u16x4 pk;
        #pragma unroll
        for (int r = 0; r < 4; ++r) pk[r] = f2b(d[r] + bq[m + r]);
        *(u16x4*)(q_t + qb + (size_t)n*QD_ + m) = pk;
      } else if (m0 < 128){
        u16x4 pk;
        #pragma unroll
        for (int r = 0; r < 4; ++r) pk[r] = f2b(d[r] + bk[m - 64 + r]);
        *(u16x4*)(k_t + qb + (size_t)n*QD_ + (m - 64)) = pk;
      } else {
        #pragma unroll
        for (int r = 0; r < 4; ++r) vb[(size_t)(m - 128 + r)*N_ + n] = f2b(d[r] + bv[m - 128 + r]);
      }
    }
  }
}

// ---------------- K3 (fused): energy + row softmax, two-pass flash-style ----------------
// Block = 512 thr (8 waves) handles one 64-row i-tile for one batch.
// Pass A: each wave streams its j-tiles (64 cols each), MFMA S=QK^T, keeps online
// running (m, l) per row in regs. Cross-wave merge via LDS. Pass B: recompute S,
// write final P = exp(S-M)/L as f32 (output) and bf16 (PV operand).
__global__ __launch_bounds__(512) void energy_softmax(const u16* __restrict__ q_t,
    const u16* __restrict__ k_t, float* __restrict__ attn, u16* __restrict__ attn_bf){
  int b = blockIdx.y;
  int i0 = blockIdx.x * 64;
  int lane = threadIdx.x & 63, w = threadIdx.x >> 6;
  int cl = lane & 15, q = lane >> 4;
  size_t qb = (size_t)b*N_*QD_;
  const u16* qbase = q_t + qb + (size_t)i0*QD_ + cl*QD_ + q*8;
  const u16* kbase = k_t + qb + cl*QD_ + q*8;

  // Q fragments for all 4 row-tiles x 2 k-steps (held in regs across both passes)
  bf16x8 af[4][2];
  #pragma unroll
  for (int t = 0; t < 4; ++t)
    #pragma unroll
    for (int kk = 0; kk < 2; ++kk)
      af[t][kk] = *(const bf16x8*)(qbase + t*16*QD_ + kk*32);

  float m_run[16], l_run[16];
  #pragma unroll
  for (int idx = 0; idx < 16; ++idx){ m_run[idx] = -3.0e38f; l_run[idx] = 0.f; }

  // ---- pass A: online max/sum ----
  for (int jt = w; jt < N_/64; jt += 8){
    const u16* kb = kbase + (size_t)jt*64*QD_;
    f32x4 acc[4][4] = {};
    #pragma unroll
    for (int kk = 0; kk < 2; ++kk){
      bf16x8 bfr[4];
      #pragma unroll
      for (int t = 0; t < 4; ++t) bfr[t] = *(const bf16x8*)(kb + t*16*QD_ + kk*32);
      #pragma unroll
      for (int tm = 0; tm < 4; ++tm)
        #pragma unroll
        for (int tn = 0; tn < 4; ++tn)
          acc[tm][tn] = __builtin_amdgcn_mfma_f32_16x16x32_bf16(af[tm][kk], bfr[tn], acc[tm][tn], 0, 0, 0);
    }
    #pragma unroll
    for (int tm = 0; tm < 4; ++tm)
      #pragma unroll
      for (int r = 0; r < 4; ++r){
        int idx = tm*4 + r;
        float mt = fmaxf(fmaxf(acc[tm][0][r], acc[tm][1][r]), fmaxf(acc[tm][2][r], acc[tm][3][r]));
        #pragma unroll
        for (int mask = 1; mask < 16; mask <<= 1) mt = fmaxf(mt, __shfl_xor(mt, mask));
        float mn = fmaxf(m_run[idx], mt);
        float st = 0.f;
        #pragma unroll
        for (int tn = 0; tn < 4; ++tn) st += __expf(acc[tm][tn][r] - mn);
        #pragma unroll
        for (int mask = 1; mask < 16; mask <<= 1) st += __shfl_xor(st, mask);
        l_run[idx] = l_run[idx]*__expf(m_run[idx] - mn) + st;
        m_run[idx] = mn;
      }
  }

  // ---- cross-wave merge ----
  __shared__ float pm[8][64], pl[8][64];
  if (cl == 0){
    #pragma unroll
    for (int idx = 0; idx < 16; ++idx){
      int row = (idx >> 2)*16 + q*4 + (idx & 3);
      pm[w][row] = m_run[idx];
      pl[w][row] = l_run[idx];
    }
  }
  __syncthreads();
  float M[16], invL[16];
  #pragma unroll
  for (int idx = 0; idx < 16; ++idx){
    int row = (idx >> 2)*16 + q*4 + (idx & 3);
    float mm = pm[0][row];
    #pragma unroll
    for (int ww = 1; ww < 8; ++ww) mm = fmaxf(mm, pm[ww][row]);
    float L = 0.f;
    #pragma unroll
    for (int ww = 0; ww < 8; ++ww) L += pl[ww][row]*__expf(pm[ww][row] - mm);
    M[idx] = mm;
    invL[idx] = 1.0f / L;
  }

  // ---- pass B: recompute S, write normalized P (f32 + bf16) ----
  float* arow = attn + (size_t)b*N_*N_ + (size_t)i0*N_;
  u16* brow = attn_bf + (size_t)b*N_*N_ + (size_t)i0*N_;
  for (int jt = w; jt < N_/64; jt += 8){
    int j0 = jt*64;
    const u16* kb = kbase + (size_t)jt*64*QD_;
    f32x4 acc[4][4] = {};
    #pragma unroll
    for (int kk = 0; kk < 2; ++kk){
      bf16x8 bfr[4];
      #pragma unroll
      for (int t = 0; t < 4; ++t) bfr[t] = *(const bf16x8*)(kb + t*16*QD_ + kk*32);
      #pragma unroll
      for (int tm = 0; tm < 4; ++tm)
        #pragma unroll
        for (int tn = 0; tn < 4; ++tn)
          acc[tm][tn] = __builtin_amdgcn_mfma_f32_16x16x32_bf16(af[tm][kk], bfr[tn], acc[tm][tn], 0, 0, 0);
    }
    #pragma unroll
    for (int tm = 0; tm < 4; ++tm)
      #pragma unroll
      for (int tn = 0; tn < 4; ++tn)
        #pragma unroll
        for (int r = 0; r < 4; ++r){
          int idx = tm*4 + r;
          float p = __expf(acc[tm][tn][r] - M[idx]) * invL[idx];
          size_t off = (size_t)(tm*16 + q*4 + r)*N_ + j0 + tn*16 + cl;
          arow[off] = p;
          brow[off] = f2b(p);
        }
  }
}

// ---------------- K4: o_t[b][i][vd] = sum_j attn_bf[i][j] * v[vd][j] ----------------
__global__ __launch_bounds__(256) void pv_gemm(const u16* __restrict__ attn_bf, const u16* __restrict__ v,
                                               u16* __restrict__ o_t){
  int b = blockIdx.z;
  int lane = threadIdx.x & 63, wid = threadIdx.x >> 6;
  int i0 = blockIdx.x*128 + (wid >> 1)*64;
  int vd0 = blockIdx.y*128 + (wid & 1)*64;
  const u16* ab = attn_bf + (size_t)b*N_*N_;
  const u16* vb = v + (size_t)b*VD_*N_;
  f32x4 acc[4][4] = {};
  mfma_tile64<N_>(ab + (size_t)i0*N_, vb + (size_t)vd0*N_, acc, lane);
  u16* ob = o_t + (size_t)b*N_*VD_;
  int cl = lane & 15, q = lane >> 4;
  #pragma unroll
  for (int tm = 0; tm < 4; ++tm){
    int i = i0 + tm*16 + q*4;
    #pragma unroll
    for (int tn = 0; tn < 4; ++tn){
      int vd = vd0 + tn*16 + cl;
      #pragma unroll
      for (int r = 0; r < 4; ++r) ob[(size_t)(i + r)*VD_ + vd] = f2b(acc[tm][tn][r]);
    }
  }
}

// ---------------- K5: out = gamma*(Wo @ o + bo) + x ----------------
__global__ __launch_bounds__(512) void out_gemm(const u16* __restrict__ Wo_bf, const u16* __restrict__ o_t,
    const float* __restrict__ bo, const float* __restrict__ gamma,
    const float* __restrict__ x, float* __restrict__ out){
  int b = blockIdx.z;
  int lane = threadIdx.x & 63, wid = threadIdx.x >> 6;
  int c0 = blockIdx.x*128 + (wid >> 2)*64;
  int n0 = blockIdx.y*256 + (wid & 3)*64;
  f32x4 acc[4][4] = {};
  mfma_tile64<VD_>(Wo_bf + (size_t)c0*VD_, o_t + (size_t)b*N_*VD_ + (size_t)n0*VD_, acc, lane);
  float g = gamma[0];
  const float* xb = x + (size_t)b*C_*N_;
  float* ob = out + (size_t)b*C_*N_;
  int cl = lane & 15, q = lane >> 4;
  #pragma unroll
  for (int tm = 0; tm < 4; ++tm){
    int c = c0 + tm*16 + q*4;
    #pragma unroll
    for (int tn = 0; tn < 4; ++tn){
      int n = n0 + tn*16 + cl;
      #pragma unroll
      for (int r = 0; r < 4; ++r){
        size_t idx = (size_t)(c + r)*N_ + n;
        ob[idx] = g*(acc[tm][tn][r] + bo[c + r]) + xb[idx];
      }
    }
  }
}

extern "C" void kernel_launch(void* const* d_in, const int* in_sizes, int n_in,
                              void* d_out, int out_size, void* d_ws, size_t ws_size,
                              hipStream_t stream){
  const float* x     = (const float*)d_in[0];
  const float* Wq    = (const float*)d_in[1];
  const float* bq    = (const float*)d_in[2];
  const float* Wk    = (const float*)d_in[3];
  const float* bk    = (const float*)d_in[4];
  const float* Wv    = (const float*)d_in[5];
  const float* bv    = (const float*)d_in[6];
  const float* Wo    = (const float*)d_in[7];
  const float* bo    = (const float*)d_in[8];
  const float* gamma = (const float*)d_in[9];

  float* out  = (float*)d_out;
  float* attn = out + (size_t)B_*C_*N_;

  char* ws = (char*)d_ws;
  u16* W_all   = (u16*)(ws + 0);             // 196,608 B
  u16* Wo_bf   = (u16*)(ws + 196608);        // 131,072 B -> 327,680
  u16* x_t     = (u16*)(ws + 327680);        // 18,874,368 -> 19,202,048
  u16* q_t     = (u16*)(ws + 19202048);      // 4,718,592  -> 23,920,640
  u16* k_t     = (u16*)(ws + 23920640);      // 4,718,592  -> 28,639,232
  u16* v       = (u16*)(ws + 28639232);      // 18,874,368 -> 47,513,600
  u16* o_t     = (u16*)(ws + 47513600);      // 18,874,368 -> 66,387,968
  u16* attn_bf = (u16*)(ws + 66387968);      // 169,869,312 -> 236,257,280

  prep_weights<<<dim3(384), 256, 0, stream>>>(Wq, Wk, Wv, Wo, W_all, Wo_bf);
  transpose_x<<<dim3(36, 4, 16), 256, 0, stream>>>(x, x_t);
  qkv_gemm<<<dim3(3, 9, 16), 512, 0, stream>>>(W_all, x_t, bq, bk, bv, q_t, k_t, v);
  energy_softmax<<<dim3(36, 16), 512, 0, stream>>>(q_t, k_t, attn, attn_bf);
  pv_gemm<<<dim3(18, 2, 16), 256, 0, stream>>>(attn_bf, v, o_t);
  out_gemm<<<dim3(2, 9, 16), 512, 0, stream>>>(Wo_bf, o_t, bo, gamma, x, out);
}